// Round 1
// baseline (794.543 us; speedup 1.0000x reference)
//
#include <hip/hip_runtime.h>
#include <cstdint>
#include <cstddef>

#define N_NODES 100000
#define E_EDGES 1600000
#define E_TOT   1700000
#define HEADS   8
#define C1      8
#define HC1     64
#define NCLS    3
#define HC2     24
#define IN_CH   500
#define NEG     0.2f

#define SEG     2048
#define NSEG    49      /* ceil(100000/2048) */

// ---------------- edge dtype detection (int32 vs int64 edge_index) -----------
// Under int64 little-endian interpretation, odd int32 positions are high words
// == 0 (values < 1e5). Under int32, they are random edge ids (certainly some
// nonzero among 4096 samples). flag=1 -> int32 mode, flag=0 -> int64 mode.
__global__ void k_detect(const int* __restrict__ ei, int* __restrict__ flag) {
  int i = blockIdx.x * blockDim.x + threadIdx.x;   // 4096 threads
  bool nz = ei[2 * i + 1] != 0;
  if (__ballot(nz)) {
    if ((threadIdx.x & 63) == 0) atomicOr(flag, 1);
  }
}

__device__ __forceinline__ int edge_at(const int* __restrict__ ei, int idx, int mode) {
  return mode ? ei[idx] : ei[2 * idx];   // int64: low word
}

// ---------------- CSR build --------------------------------------------------
__global__ void k_hist(const int* __restrict__ ei, const int* __restrict__ flag,
                       int* __restrict__ deg) {
  int e = blockIdx.x * blockDim.x + threadIdx.x;
  if (e >= E_TOT) return;
  int mode = *flag;
  int d = (e < E_EDGES) ? edge_at(ei, E_EDGES + e, mode) : (e - E_EDGES);
  atomicAdd(&deg[d], 1);
}

__global__ void k_seg_sum(const int* __restrict__ deg, int* __restrict__ segsum) {
  __shared__ int sh[256];
  int tid = threadIdx.x;
  int base = blockIdx.x * SEG;
  int sum = 0;
#pragma unroll
  for (int j = 0; j < 8; ++j) {
    int idx = base + j * 256 + tid;
    if (idx < N_NODES) sum += deg[idx];
  }
  sh[tid] = sum; __syncthreads();
  for (int off = 128; off > 0; off >>= 1) {
    if (tid < off) sh[tid] += sh[tid + off];
    __syncthreads();
  }
  if (tid == 0) segsum[blockIdx.x] = sh[0];
}

__global__ void k_scan_small(const int* __restrict__ segsum, int* __restrict__ segoff,
                             int* __restrict__ rowptr) {
  if (threadIdx.x == 0 && blockIdx.x == 0) {
    int run = 0;
    for (int s = 0; s < NSEG; ++s) { int t = segsum[s]; segoff[s] = run; run += t; }
    rowptr[N_NODES] = run;   // == E_TOT
  }
}

__global__ void k_seg_scan(const int* __restrict__ deg, const int* __restrict__ segoff,
                           int* __restrict__ rowptr) {
  __shared__ int sh[256];
  int tid = threadIdx.x;
  int idx0 = blockIdx.x * SEG + tid * 8;
  int v[8]; int tsum = 0;
#pragma unroll
  for (int j = 0; j < 8; ++j) {
    int idx = idx0 + j;
    v[j] = (idx < N_NODES) ? deg[idx] : 0;
    tsum += v[j];
  }
  sh[tid] = tsum; __syncthreads();
  for (int off = 1; off < 256; off <<= 1) {
    int add = (tid >= off) ? sh[tid - off] : 0;
    __syncthreads();
    sh[tid] += add;
    __syncthreads();
  }
  int run = segoff[blockIdx.x] + sh[tid] - tsum;   // exclusive prefix
#pragma unroll
  for (int j = 0; j < 8; ++j) {
    int idx = idx0 + j;
    if (idx < N_NODES) rowptr[idx] = run;
    run += v[j];
  }
}

__global__ void k_scatter(const int* __restrict__ ei, const int* __restrict__ flag,
                          const int* __restrict__ rowptr, int* __restrict__ cnt,
                          int* __restrict__ esrc) {
  int e = blockIdx.x * blockDim.x + threadIdx.x;
  if (e >= E_TOT) return;
  int mode = *flag;
  int s, d;
  if (e < E_EDGES) { s = edge_at(ei, e, mode); d = edge_at(ei, E_EDGES + e, mode); }
  else             { s = e - E_EDGES; d = s; }
  int pos = rowptr[d] + atomicAdd(&cnt[d], 1);
  esrc[pos] = s;
}

// ---------------- GEMM1: xl1 = x@W1l, xr1 = x@W1r  (fp32, fused) -------------
#define BM 128
#define KB 32
__global__ __launch_bounds__(256) void k_gemm1(const float* __restrict__ x,
    const float* __restrict__ Wl, const float* __restrict__ Wr,
    float* __restrict__ xl, float* __restrict__ xr) {
  __shared__ float wlds[KB][128];
  __shared__ float xlds[BM][KB + 1];   // +1 pad: conflict-free column reads
  const int tid = threadIdx.x;
  const int cg  = tid & 7;     // 8 col groups x 16 cols
  const int rq  = tid >> 3;    // 32 row quads
  const int r0  = rq * 4;
  const int bm0 = blockIdx.x * BM;
  float acc[4][16];
#pragma unroll
  for (int i = 0; i < 4; ++i)
#pragma unroll
    for (int j = 0; j < 16; ++j) acc[i][j] = 0.f;

  for (int k0 = 0; k0 < IN_CH; k0 += KB) {
#pragma unroll
    for (int i = 0; i < 16; ++i) {           // W chunk [KB][128]
      int idx = i * 256 + tid;
      int kk = idx >> 7, col = idx & 127;
      int k = k0 + kk;
      float v = 0.f;
      if (k < IN_CH) v = (col < HC1) ? Wl[k * HC1 + col] : Wr[k * HC1 + col - HC1];
      wlds[kk][col] = v;
    }
#pragma unroll
    for (int i = 0; i < 16; ++i) {           // x chunk [BM][KB]
      int idx = i * 256 + tid;
      int row = idx >> 5, kk = idx & 31;
      int gr = bm0 + row, k = k0 + kk;
      xlds[row][kk] = (gr < N_NODES && k < IN_CH) ? x[(size_t)gr * IN_CH + k] : 0.f;
    }
    __syncthreads();
#pragma unroll 4
    for (int kk = 0; kk < KB; ++kk) {
      float xv[4];
#pragma unroll
      for (int i = 0; i < 4; ++i) xv[i] = xlds[r0 + i][kk];
      float4 w4[4];
#pragma unroll
      for (int j4 = 0; j4 < 4; ++j4)
        w4[j4] = *(const float4*)&wlds[kk][cg * 16 + j4 * 4];
#pragma unroll
      for (int i = 0; i < 4; ++i) {
#pragma unroll
        for (int j4 = 0; j4 < 4; ++j4) {
          acc[i][j4*4+0] = fmaf(xv[i], w4[j4].x, acc[i][j4*4+0]);
          acc[i][j4*4+1] = fmaf(xv[i], w4[j4].y, acc[i][j4*4+1]);
          acc[i][j4*4+2] = fmaf(xv[i], w4[j4].z, acc[i][j4*4+2]);
          acc[i][j4*4+3] = fmaf(xv[i], w4[j4].w, acc[i][j4*4+3]);
        }
      }
    }
    __syncthreads();
  }
  float* dst = (cg < 4) ? xl : xr;
  const int cb = (cg & 3) * 16;
#pragma unroll
  for (int i = 0; i < 4; ++i) {
    int gr = bm0 + r0 + i;
    if (gr < N_NODES) {
#pragma unroll
      for (int j4 = 0; j4 < 4; ++j4) {
        float4 v = make_float4(acc[i][j4*4+0], acc[i][j4*4+1], acc[i][j4*4+2], acc[i][j4*4+3]);
        *(float4*)&dst[(size_t)gr * HC1 + cb + j4 * 4] = v;
      }
    }
  }
}

// ---------------- layer-1 edge pass: online segment softmax + aggregate ------
// thread = (node, head); 8 consecutive lanes = 8 heads of one node -> the
// 256B xl row gather is coalesced across the group.
__global__ __launch_bounds__(256) void k_edge1(const float* __restrict__ xl1,
    const float* __restrict__ xr1, const float* __restrict__ att1,
    const float* __restrict__ b1, const int* __restrict__ rowptr,
    const int* __restrict__ esrc, float* __restrict__ hbuf) {
  int t = blockIdx.x * blockDim.x + threadIdx.x;   // exact grid: N*8
  int node = t >> 3, h = t & 7;
  const float4* xrp = (const float4*)(xr1 + (size_t)node * HC1 + h * C1);
  float4 xa = xrp[0], xb = xrp[1];
  float xrv[8] = {xa.x, xa.y, xa.z, xa.w, xb.x, xb.y, xb.z, xb.w};
  const float4* ap = (const float4*)(att1 + h * C1);
  float4 aa = ap[0], ab = ap[1];
  float av[8] = {aa.x, aa.y, aa.z, aa.w, ab.x, ab.y, ab.z, ab.w};

  float m = -INFINITY, s = 0.f;
  float acc[8];
#pragma unroll
  for (int c = 0; c < 8; ++c) acc[c] = 0.f;

  int beg = rowptr[node], end = rowptr[node + 1];
  for (int i = beg; i < end; ++i) {
    int sn = esrc[i];
    const float4* xlp = (const float4*)(xl1 + (size_t)sn * HC1 + h * C1);
    float4 la = xlp[0], lb = xlp[1];
    float xlv[8] = {la.x, la.y, la.z, la.w, lb.x, lb.y, lb.z, lb.w};
    float logit = 0.f;
#pragma unroll
    for (int c = 0; c < 8; ++c) {
      float u = xlv[c] + xrv[c];
      u = (u > 0.f) ? u : NEG * u;
      logit = fmaf(u, av[c], logit);
    }
    float mn = fmaxf(m, logit);
    float so = __expf(m - mn);       // 0 on first edge (m=-inf, mn finite)
    float p  = __expf(logit - mn);
    s = s * so + p;
#pragma unroll
    for (int c = 0; c < 8; ++c) acc[c] = fmaf(acc[c], so, p * xlv[c]);
    m = mn;
  }
  float inv = 1.f / s;
  float o[8];
#pragma unroll
  for (int c = 0; c < 8; ++c) {
    float v = fmaf(acc[c], inv, b1[h * C1 + c]);
    o[c] = (v > 0.f) ? v : expm1f(v);    // ELU
  }
  float4* hp = (float4*)(hbuf + (size_t)node * HC1 + h * C1);
  hp[0] = make_float4(o[0], o[1], o[2], o[3]);
  hp[1] = make_float4(o[4], o[5], o[6], o[7]);
}

// ---------------- GEMM2: xl2 = h@W2l, xr2 = h@W2r  (64 -> 24 each) -----------
__global__ __launch_bounds__(256) void k_gemm2(const float* __restrict__ hbuf,
    const float* __restrict__ W2l, const float* __restrict__ W2r,
    float* __restrict__ xl2, float* __restrict__ xr2) {
  __shared__ float w[64][48];
  int tid = threadIdx.x;
  for (int i = tid; i < 64 * 48; i += 256) {
    int k = i / 48, j = i - k * 48;
    w[k][j] = (j < HC2) ? W2l[k * HC2 + j] : W2r[k * HC2 + (j - HC2)];
  }
  __syncthreads();
  int node = blockIdx.x * 256 + tid;
  if (node >= N_NODES) return;
  float acc[48];
#pragma unroll
  for (int j = 0; j < 48; ++j) acc[j] = 0.f;
  const float4* hp = (const float4*)(hbuf + (size_t)node * HC1);
  for (int k0 = 0; k0 < 64; k0 += 16) {
    float rv[16];
#pragma unroll
    for (int q = 0; q < 4; ++q) {
      float4 r4 = hp[k0 / 4 + q];
      rv[q*4+0] = r4.x; rv[q*4+1] = r4.y; rv[q*4+2] = r4.z; rv[q*4+3] = r4.w;
    }
#pragma unroll
    for (int kk = 0; kk < 16; ++kk) {
      float hv = rv[kk];
      const float4* wrow = (const float4*)&w[k0 + kk][0];
#pragma unroll
      for (int j4 = 0; j4 < 12; ++j4) {
        float4 wv = wrow[j4];
        acc[j4*4+0] = fmaf(hv, wv.x, acc[j4*4+0]);
        acc[j4*4+1] = fmaf(hv, wv.y, acc[j4*4+1]);
        acc[j4*4+2] = fmaf(hv, wv.z, acc[j4*4+2]);
        acc[j4*4+3] = fmaf(hv, wv.w, acc[j4*4+3]);
      }
    }
  }
  float4* lp = (float4*)(xl2 + (size_t)node * HC2);
  float4* rp = (float4*)(xr2 + (size_t)node * HC2);
#pragma unroll
  for (int j4 = 0; j4 < 6; ++j4) {
    lp[j4] = make_float4(acc[j4*4+0], acc[j4*4+1], acc[j4*4+2], acc[j4*4+3]);
    rp[j4] = make_float4(acc[24+j4*4+0], acc[24+j4*4+1], acc[24+j4*4+2], acc[24+j4*4+3]);
  }
}

// ---------------- layer-2 edge pass + head-mean + final softmax --------------
__global__ __launch_bounds__(256) void k_edge2(const float* __restrict__ xl2,
    const float* __restrict__ xr2, const float* __restrict__ att2,
    const float* __restrict__ b2, const int* __restrict__ rowptr,
    const int* __restrict__ esrc, float* __restrict__ out) {
  int t = blockIdx.x * blockDim.x + threadIdx.x;   // exact grid: N*8
  int node = t >> 3, h = t & 7;
  float xrv[3], av[3];
#pragma unroll
  for (int c = 0; c < 3; ++c) {
    xrv[c] = xr2[(size_t)node * HC2 + h * NCLS + c];
    av[c]  = att2[h * NCLS + c];
  }
  float m = -INFINITY, s = 0.f;
  float acc[3] = {0.f, 0.f, 0.f};
  int beg = rowptr[node], end = rowptr[node + 1];
  for (int i = beg; i < end; ++i) {
    int sn = esrc[i];
    float xlv[3];
#pragma unroll
    for (int c = 0; c < 3; ++c) xlv[c] = xl2[(size_t)sn * HC2 + h * NCLS + c];
    float logit = 0.f;
#pragma unroll
    for (int c = 0; c < 3; ++c) {
      float u = xlv[c] + xrv[c];
      u = (u > 0.f) ? u : NEG * u;
      logit = fmaf(u, av[c], logit);
    }
    float mn = fmaxf(m, logit);
    float so = __expf(m - mn);
    float p  = __expf(logit - mn);
    s = s * so + p;
#pragma unroll
    for (int c = 0; c < 3; ++c) acc[c] = fmaf(acc[c], so, p * xlv[c]);
    m = mn;
  }
  float inv = 1.f / s;
  float o[3];
#pragma unroll
  for (int c = 0; c < 3; ++c) o[c] = acc[c] * inv;
  // mean over 8 heads (8-lane group butterfly; grid exact so all lanes live)
#pragma unroll
  for (int off = 1; off < 8; off <<= 1) {
#pragma unroll
    for (int c = 0; c < 3; ++c) o[c] += __shfl_xor(o[c], off);
  }
  if (h < 3) {
    float z[3];
#pragma unroll
    for (int c = 0; c < 3; ++c) z[c] = o[c] * 0.125f + b2[c];
    float mx = fmaxf(fmaxf(z[0], z[1]), z[2]);
    float e0 = __expf(z[0] - mx), e1 = __expf(z[1] - mx), e2 = __expf(z[2] - mx);
    float sum = e0 + e1 + e2;
    float num = (h == 0) ? e0 : (h == 1) ? e1 : e2;
    out[(size_t)node * NCLS + h] = num / sum;
  }
}

// ---------------- launch -----------------------------------------------------
extern "C" void kernel_launch(void* const* d_in, const int* in_sizes, int n_in,
                              void* d_out, int out_size, void* d_ws, size_t ws_size,
                              hipStream_t stream) {
  (void)in_sizes; (void)n_in; (void)out_size; (void)ws_size;
  const float* x    = (const float*)d_in[0];
  const int*   ei   = (const int*)d_in[1];
  const float* W1l  = (const float*)d_in[2];
  const float* W1r  = (const float*)d_in[3];
  const float* att1 = (const float*)d_in[4];
  const float* b1   = (const float*)d_in[5];
  const float* W2l  = (const float*)d_in[6];
  const float* W2r  = (const float*)d_in[7];
  const float* att2 = (const float*)d_in[8];
  const float* b2   = (const float*)d_in[9];
  float* out = (float*)d_out;

  char* w = (char*)d_ws;
  float* xl1  = (float*)(w);                 // 25.6 MB
  float* xr1  = (float*)(w + 25600000);      // 25.6 MB
  float* hbuf = (float*)(w + 51200000);      // 25.6 MB
  float* xl2  = (float*)(w);                 // overlays xl1 (dead after edge1)
  float* xr2  = (float*)(w + 9600000);       // inside old xl1 region
  char* ip = w + 76800000;
  int* deg    = (int*)(ip);                  // 400000 B
  int* cnt    = (int*)(ip + 400000);         // 400000 B
  int* rowptr = (int*)(ip + 800000);         // 400004 B
  int* segsum = (int*)(ip + 1200256);
  int* segoff = (int*)(ip + 1200512);
  int* flag   = (int*)(ip + 1200768);
  int* esrc   = (int*)(ip + 1201024);        // 6.8 MB  -> total ~84.8 MB

  hipMemsetAsync(deg, 0, 800000, stream);    // deg + cnt (contiguous)
  hipMemsetAsync(flag, 0, 4, stream);

  k_detect   <<<16, 256, 0, stream>>>(ei, flag);
  k_hist     <<<(E_TOT + 255) / 256, 256, 0, stream>>>(ei, flag, deg);
  k_seg_sum  <<<NSEG, 256, 0, stream>>>(deg, segsum);
  k_scan_small<<<1, 64, 0, stream>>>(segsum, segoff, rowptr);
  k_seg_scan <<<NSEG, 256, 0, stream>>>(deg, segoff, rowptr);
  k_scatter  <<<(E_TOT + 255) / 256, 256, 0, stream>>>(ei, flag, rowptr, cnt, esrc);
  k_gemm1    <<<(N_NODES + BM - 1) / BM, 256, 0, stream>>>(x, W1l, W1r, xl1, xr1);
  k_edge1    <<<(N_NODES * HEADS) / 256, 256, 0, stream>>>(xl1, xr1, att1, b1, rowptr, esrc, hbuf);
  k_gemm2    <<<(N_NODES + 255) / 256, 256, 0, stream>>>(hbuf, W2l, W2r, xl2, xr2);
  k_edge2    <<<(N_NODES * HEADS) / 256, 256, 0, stream>>>(xl2, xr2, att2, b2, rowptr, esrc, out);
}

// Round 2
// 444.086 us; speedup vs baseline: 1.7892x; 1.7892x over previous
//
#include <hip/hip_runtime.h>
#include <cstdint>
#include <cstddef>

#define N_NODES 100000
#define E_EDGES 1600000
#define E_TOT   1700000
#define HEADS   8
#define C1      8
#define HC1     64
#define NCLS    3
#define HC2     24
#define IN_CH   500
#define NEG     0.2f

#define SEG     2048
#define NSEG    49      /* ceil(100000/2048) */

typedef __attribute__((ext_vector_type(8))) short bf16x8;
typedef __attribute__((ext_vector_type(4))) float f32x4;

__device__ __forceinline__ unsigned short f2bf(float f) {
  unsigned u = __float_as_uint(f);
  u += 0x7FFFu + ((u >> 16) & 1u);
  return (unsigned short)(u >> 16);
}
__device__ __forceinline__ float bfhi(unsigned short h) {
  return __uint_as_float(((unsigned)h) << 16);
}

// ---------------- edge dtype detection (int32 vs int64 edge_index) -----------
__global__ void k_detect(const int* __restrict__ ei, int* __restrict__ flag) {
  int i = blockIdx.x * blockDim.x + threadIdx.x;   // 4096 threads
  bool nz = ei[2 * i + 1] != 0;
  if (__ballot(nz)) {
    if ((threadIdx.x & 63) == 0) atomicOr(flag, 1);
  }
}

__device__ __forceinline__ int edge_at(const int* __restrict__ ei, int idx, int mode) {
  return mode ? ei[idx] : ei[2 * idx];   // int64: low word
}

// ---------------- CSR build --------------------------------------------------
__global__ void k_hist(const int* __restrict__ ei, const int* __restrict__ flag,
                       int* __restrict__ deg) {
  int e = blockIdx.x * blockDim.x + threadIdx.x;
  if (e >= E_TOT) return;
  int mode = *flag;
  int d = (e < E_EDGES) ? edge_at(ei, E_EDGES + e, mode) : (e - E_EDGES);
  atomicAdd(&deg[d], 1);
}

__global__ void k_seg_sum(const int* __restrict__ deg, int* __restrict__ segsum) {
  __shared__ int sh[256];
  int tid = threadIdx.x;
  int base = blockIdx.x * SEG;
  int sum = 0;
#pragma unroll
  for (int j = 0; j < 8; ++j) {
    int idx = base + j * 256 + tid;
    if (idx < N_NODES) sum += deg[idx];
  }
  sh[tid] = sum; __syncthreads();
  for (int off = 128; off > 0; off >>= 1) {
    if (tid < off) sh[tid] += sh[tid + off];
    __syncthreads();
  }
  if (tid == 0) segsum[blockIdx.x] = sh[0];
}

__global__ void k_scan_small(const int* __restrict__ segsum, int* __restrict__ segoff,
                             int* __restrict__ rowptr) {
  if (threadIdx.x == 0 && blockIdx.x == 0) {
    int run = 0;
    for (int s = 0; s < NSEG; ++s) { int t = segsum[s]; segoff[s] = run; run += t; }
    rowptr[N_NODES] = run;   // == E_TOT
  }
}

__global__ void k_seg_scan(const int* __restrict__ deg, const int* __restrict__ segoff,
                           int* __restrict__ rowptr) {
  __shared__ int sh[256];
  int tid = threadIdx.x;
  int idx0 = blockIdx.x * SEG + tid * 8;
  int v[8]; int tsum = 0;
#pragma unroll
  for (int j = 0; j < 8; ++j) {
    int idx = idx0 + j;
    v[j] = (idx < N_NODES) ? deg[idx] : 0;
    tsum += v[j];
  }
  sh[tid] = tsum; __syncthreads();
  for (int off = 1; off < 256; off <<= 1) {
    int add = (tid >= off) ? sh[tid - off] : 0;
    __syncthreads();
    sh[tid] += add;
    __syncthreads();
  }
  int run = segoff[blockIdx.x] + sh[tid] - tsum;   // exclusive prefix
#pragma unroll
  for (int j = 0; j < 8; ++j) {
    int idx = idx0 + j;
    if (idx < N_NODES) rowptr[idx] = run;
    run += v[j];
  }
}

__global__ void k_scatter(const int* __restrict__ ei, const int* __restrict__ flag,
                          const int* __restrict__ rowptr, int* __restrict__ cnt,
                          int* __restrict__ esrc) {
  int e = blockIdx.x * blockDim.x + threadIdx.x;
  if (e >= E_TOT) return;
  int mode = *flag;
  int s, d;
  if (e < E_EDGES) { s = edge_at(ei, e, mode); d = edge_at(ei, E_EDGES + e, mode); }
  else             { s = e - E_EDGES; d = s; }
  int pos = rowptr[d] + atomicAdd(&cnt[d], 1);
  esrc[pos] = s;
}

// ---------------- W1 pre-convert: fp32 [500][128] -> bf16 hi/lo, [N=128][K=512]
__global__ void k_wconv(const float* __restrict__ W1l, const float* __restrict__ W1r,
                        unsigned short* __restrict__ WtHi, unsigned short* __restrict__ WtLo) {
  int t = blockIdx.x * 256 + threadIdx.x;   // 65536 = 128*512
  int n = t >> 9, k = t & 511;
  float v = 0.f;
  if (k < IN_CH) v = (n < HC1) ? W1l[k * HC1 + n] : W1r[k * HC1 + (n - HC1)];
  unsigned short h = f2bf(v);
  unsigned short l = f2bf(v - bfhi(h));
  WtHi[n * 512 + k] = h;
  WtLo[n * 512 + k] = l;
}

// ---------------- GEMM1 via split-bf16 MFMA ----------------------------------
// C[128 x 128] per block; 4 waves in 2x2, each owns 64x64.
// A (x rows) and B (W cols) both stored [row][K=64] bf16 in LDS, XOR-swizzled.
#define A_HI 0
#define A_LO 16384
#define B_HI 32768
#define B_LO 49152

__global__ __launch_bounds__(256, 2) void k_gemm1(const float* __restrict__ x,
    const unsigned short* __restrict__ WtHi, const unsigned short* __restrict__ WtLo,
    float* __restrict__ xl, float* __restrict__ xr) {
  __shared__ char lds[65536];
  const int tid  = threadIdx.x;
  const int bm0  = blockIdx.x * 128;
  const int lane = tid & 63, wid = tid >> 6;
  const int wr   = wid >> 1, wc = wid & 1;
  const int lrow = lane & 15, kg = lane >> 4;

  f32x4 acc[4][4];
#pragma unroll
  for (int m = 0; m < 4; ++m)
#pragma unroll
    for (int n = 0; n < 4; ++n) acc[m][n] = (f32x4){0.f, 0.f, 0.f, 0.f};

  for (int ks = 0; ks < 8; ++ks) {
    const int k0 = ks * 64;
    // ---- stage A: load x fp32, split to bf16 hi/lo, swizzled LDS write
#pragma unroll
    for (int i = 0; i < 8; ++i) {
      int flat = i * 256 + tid;
      int r = flat >> 4, c4 = flat & 15;
      int grow = bm0 + r, k = k0 + c4 * 4;
      float4 v = make_float4(0.f, 0.f, 0.f, 0.f);
      if (grow < N_NODES && k < IN_CH)      // IN_CH=500 divisible by 4 -> full float4 valid
        v = *(const float4*)&x[(size_t)grow * IN_CH + k];
      ushort4 h, l;
      h.x = f2bf(v.x); l.x = f2bf(v.x - bfhi(h.x));
      h.y = f2bf(v.y); l.y = f2bf(v.y - bfhi(h.y));
      h.z = f2bf(v.z); l.z = f2bf(v.z - bfhi(h.z));
      h.w = f2bf(v.w); l.w = f2bf(v.w - bfhi(h.w));
      int boff = (r * 128 + c4 * 8) ^ ((r & 7) << 4);
      *(ushort4*)(lds + A_HI + boff) = h;
      *(ushort4*)(lds + A_LO + boff) = l;
    }
    // ---- stage B: copy pre-converted Wt tiles, swizzled
#pragma unroll
    for (int i = 0; i < 4; ++i) {
      int flat = i * 256 + tid;
      int n = flat >> 3, c = flat & 7;
      int src = n * 512 + k0 + c * 8;
      uint4 vh = *(const uint4*)&WtHi[src];
      uint4 vl = *(const uint4*)&WtLo[src];
      int boff = (n * 128 + c * 16) ^ ((n & 7) << 4);
      *(uint4*)(lds + B_HI + boff) = vh;
      *(uint4*)(lds + B_LO + boff) = vl;
    }
    __syncthreads();
    // ---- compute: 2 K-halves x 16 tiles x 3 precision products
#pragma unroll
    for (int kk = 0; kk < 2; ++kk) {
      const int kbyte = kk * 64 + kg * 16;
      bf16x8 ah[4], al[4], bh[4], bl[4];
#pragma unroll
      for (int m = 0; m < 4; ++m) {
        int row = wr * 64 + m * 16 + lrow;
        int off = (row * 128 + kbyte) ^ ((row & 7) << 4);
        ah[m] = *(const bf16x8*)(lds + A_HI + off);
        al[m] = *(const bf16x8*)(lds + A_LO + off);
      }
#pragma unroll
      for (int n = 0; n < 4; ++n) {
        int row = wc * 64 + n * 16 + lrow;
        int off = (row * 128 + kbyte) ^ ((row & 7) << 4);
        bh[n] = *(const bf16x8*)(lds + B_HI + off);
        bl[n] = *(const bf16x8*)(lds + B_LO + off);
      }
#pragma unroll
      for (int m = 0; m < 4; ++m)
#pragma unroll
        for (int n = 0; n < 4; ++n) {
          acc[m][n] = __builtin_amdgcn_mfma_f32_16x16x32_bf16(ah[m], bh[n], acc[m][n], 0, 0, 0);
          acc[m][n] = __builtin_amdgcn_mfma_f32_16x16x32_bf16(ah[m], bl[n], acc[m][n], 0, 0, 0);
          acc[m][n] = __builtin_amdgcn_mfma_f32_16x16x32_bf16(al[m], bh[n], acc[m][n], 0, 0, 0);
        }
    }
    __syncthreads();
  }
  // ---- store: D col = lane&15, row = (lane>>4)*4 + reg
#pragma unroll
  for (int m = 0; m < 4; ++m)
#pragma unroll
    for (int n = 0; n < 4; ++n) {
      int gcol = wc * 64 + n * 16 + lrow;
      float* dst = (gcol < HC1) ? xl : xr;
      int cc = gcol & 63;
#pragma unroll
      for (int j = 0; j < 4; ++j) {
        int grow = bm0 + wr * 64 + m * 16 + kg * 4 + j;
        if (grow < N_NODES) dst[(size_t)grow * HC1 + cc] = acc[m][n][j];
      }
    }
}

// ---------------- layer-1 edge pass: online segment softmax + aggregate ------
__global__ __launch_bounds__(256) void k_edge1(const float* __restrict__ xl1,
    const float* __restrict__ xr1, const float* __restrict__ att1,
    const float* __restrict__ b1, const int* __restrict__ rowptr,
    const int* __restrict__ esrc, float* __restrict__ hbuf) {
  int t = blockIdx.x * blockDim.x + threadIdx.x;   // exact grid: N*8
  int node = t >> 3, h = t & 7;
  const float4* xrp = (const float4*)(xr1 + (size_t)node * HC1 + h * C1);
  float4 xa = xrp[0], xb = xrp[1];
  float xrv[8] = {xa.x, xa.y, xa.z, xa.w, xb.x, xb.y, xb.z, xb.w};
  const float4* ap = (const float4*)(att1 + h * C1);
  float4 aa = ap[0], ab = ap[1];
  float av[8] = {aa.x, aa.y, aa.z, aa.w, ab.x, ab.y, ab.z, ab.w};

  float m = -INFINITY, s = 0.f;
  float acc[8];
#pragma unroll
  for (int c = 0; c < 8; ++c) acc[c] = 0.f;

  int beg = rowptr[node], end = rowptr[node + 1];
  for (int i = beg; i < end; ++i) {
    int sn = esrc[i];
    const float4* xlp = (const float4*)(xl1 + (size_t)sn * HC1 + h * C1);
    float4 la = xlp[0], lb = xlp[1];
    float xlv[8] = {la.x, la.y, la.z, la.w, lb.x, lb.y, lb.z, lb.w};
    float logit = 0.f;
#pragma unroll
    for (int c = 0; c < 8; ++c) {
      float u = xlv[c] + xrv[c];
      u = (u > 0.f) ? u : NEG * u;
      logit = fmaf(u, av[c], logit);
    }
    float mn = fmaxf(m, logit);
    float so = __expf(m - mn);       // 0 on first edge (m=-inf, mn finite)
    float p  = __expf(logit - mn);
    s = s * so + p;
#pragma unroll
    for (int c = 0; c < 8; ++c) acc[c] = fmaf(acc[c], so, p * xlv[c]);
    m = mn;
  }
  float inv = 1.f / s;
  float o[8];
#pragma unroll
  for (int c = 0; c < 8; ++c) {
    float v = fmaf(acc[c], inv, b1[h * C1 + c]);
    o[c] = (v > 0.f) ? v : expm1f(v);    // ELU
  }
  float4* hp = (float4*)(hbuf + (size_t)node * HC1 + h * C1);
  hp[0] = make_float4(o[0], o[1], o[2], o[3]);
  hp[1] = make_float4(o[4], o[5], o[6], o[7]);
}

// ---------------- GEMM2: xl2 = h@W2l, xr2 = h@W2r  (64 -> 24 each) -----------
__global__ __launch_bounds__(256) void k_gemm2(const float* __restrict__ hbuf,
    const float* __restrict__ W2l, const float* __restrict__ W2r,
    float* __restrict__ xl2, float* __restrict__ xr2) {
  __shared__ float w[64][48];
  int tid = threadIdx.x;
  for (int i = tid; i < 64 * 48; i += 256) {
    int k = i / 48, j = i - k * 48;
    w[k][j] = (j < HC2) ? W2l[k * HC2 + j] : W2r[k * HC2 + (j - HC2)];
  }
  __syncthreads();
  int node = blockIdx.x * 256 + tid;
  if (node >= N_NODES) return;
  float acc[48];
#pragma unroll
  for (int j = 0; j < 48; ++j) acc[j] = 0.f;
  const float4* hp = (const float4*)(hbuf + (size_t)node * HC1);
  for (int k0 = 0; k0 < 64; k0 += 16) {
    float rv[16];
#pragma unroll
    for (int q = 0; q < 4; ++q) {
      float4 r4 = hp[k0 / 4 + q];
      rv[q*4+0] = r4.x; rv[q*4+1] = r4.y; rv[q*4+2] = r4.z; rv[q*4+3] = r4.w;
    }
#pragma unroll
    for (int kk = 0; kk < 16; ++kk) {
      float hv = rv[kk];
      const float4* wrow = (const float4*)&w[k0 + kk][0];
#pragma unroll
      for (int j4 = 0; j4 < 12; ++j4) {
        float4 wv = wrow[j4];
        acc[j4*4+0] = fmaf(hv, wv.x, acc[j4*4+0]);
        acc[j4*4+1] = fmaf(hv, wv.y, acc[j4*4+1]);
        acc[j4*4+2] = fmaf(hv, wv.z, acc[j4*4+2]);
        acc[j4*4+3] = fmaf(hv, wv.w, acc[j4*4+3]);
      }
    }
  }
  float4* lp = (float4*)(xl2 + (size_t)node * HC2);
  float4* rp = (float4*)(xr2 + (size_t)node * HC2);
#pragma unroll
  for (int j4 = 0; j4 < 6; ++j4) {
    lp[j4] = make_float4(acc[j4*4+0], acc[j4*4+1], acc[j4*4+2], acc[j4*4+3]);
    rp[j4] = make_float4(acc[24+j4*4+0], acc[24+j4*4+1], acc[24+j4*4+2], acc[24+j4*4+3]);
  }
}

// ---------------- layer-2 edge pass + head-mean + final softmax --------------
__global__ __launch_bounds__(256) void k_edge2(const float* __restrict__ xl2,
    const float* __restrict__ xr2, const float* __restrict__ att2,
    const float* __restrict__ b2, const int* __restrict__ rowptr,
    const int* __restrict__ esrc, float* __restrict__ out) {
  int t = blockIdx.x * blockDim.x + threadIdx.x;   // exact grid: N*8
  int node = t >> 3, h = t & 7;
  float xrv[3], av[3];
#pragma unroll
  for (int c = 0; c < 3; ++c) {
    xrv[c] = xr2[(size_t)node * HC2 + h * NCLS + c];
    av[c]  = att2[h * NCLS + c];
  }
  float m = -INFINITY, s = 0.f;
  float acc[3] = {0.f, 0.f, 0.f};
  int beg = rowptr[node], end = rowptr[node + 1];
  for (int i = beg; i < end; ++i) {
    int sn = esrc[i];
    float xlv[3];
#pragma unroll
    for (int c = 0; c < 3; ++c) xlv[c] = xl2[(size_t)sn * HC2 + h * NCLS + c];
    float logit = 0.f;
#pragma unroll
    for (int c = 0; c < 3; ++c) {
      float u = xlv[c] + xrv[c];
      u = (u > 0.f) ? u : NEG * u;
      logit = fmaf(u, av[c], logit);
    }
    float mn = fmaxf(m, logit);
    float so = __expf(m - mn);
    float p  = __expf(logit - mn);
    s = s * so + p;
#pragma unroll
    for (int c = 0; c < 3; ++c) acc[c] = fmaf(acc[c], so, p * xlv[c]);
    m = mn;
  }
  float inv = 1.f / s;
  float o[3];
#pragma unroll
  for (int c = 0; c < 3; ++c) o[c] = acc[c] * inv;
  // mean over 8 heads (8-lane group butterfly; grid exact so all lanes live)
#pragma unroll
  for (int off = 1; off < 8; off <<= 1) {
#pragma unroll
    for (int c = 0; c < 3; ++c) o[c] += __shfl_xor(o[c], off);
  }
  if (h < 3) {
    float z[3];
#pragma unroll
    for (int c = 0; c < 3; ++c) z[c] = o[c] * 0.125f + b2[c];
    float mx = fmaxf(fmaxf(z[0], z[1]), z[2]);
    float e0 = __expf(z[0] - mx), e1 = __expf(z[1] - mx), e2 = __expf(z[2] - mx);
    float sum = e0 + e1 + e2;
    float num = (h == 0) ? e0 : (h == 1) ? e1 : e2;
    out[(size_t)node * NCLS + h] = num / sum;
  }
}

// ---------------- launch -----------------------------------------------------
extern "C" void kernel_launch(void* const* d_in, const int* in_sizes, int n_in,
                              void* d_out, int out_size, void* d_ws, size_t ws_size,
                              hipStream_t stream) {
  (void)in_sizes; (void)n_in; (void)out_size; (void)ws_size;
  const float* x    = (const float*)d_in[0];
  const int*   ei   = (const int*)d_in[1];
  const float* W1l  = (const float*)d_in[2];
  const float* W1r  = (const float*)d_in[3];
  const float* att1 = (const float*)d_in[4];
  const float* b1   = (const float*)d_in[5];
  const float* W2l  = (const float*)d_in[6];
  const float* W2r  = (const float*)d_in[7];
  const float* att2 = (const float*)d_in[8];
  const float* b2   = (const float*)d_in[9];
  float* out = (float*)d_out;

  char* w = (char*)d_ws;
  float* xl1  = (float*)(w);                 // 25.6 MB
  float* xr1  = (float*)(w + 25600000);      // 25.6 MB
  float* hbuf = (float*)(w + 51200000);      // 25.6 MB (Wt tables live here pre-edge1)
  float* xl2  = (float*)(w);                 // overlays xl1 (dead after edge1)
  float* xr2  = (float*)(w + 9600000);       // inside old xl1 region
  unsigned short* WtHi = (unsigned short*)(w + 51200000);           // 128 KB
  unsigned short* WtLo = (unsigned short*)(w + 51200000 + 131072);  // 128 KB
  char* ip = w + 76800000;
  int* deg    = (int*)(ip);                  // 400000 B
  int* cnt    = (int*)(ip + 400000);         // 400000 B
  int* rowptr = (int*)(ip + 800000);         // 400004 B
  int* segsum = (int*)(ip + 1200256);
  int* segoff = (int*)(ip + 1200512);
  int* flag   = (int*)(ip + 1200768);
  int* esrc   = (int*)(ip + 1201024);        // 6.8 MB  -> total ~84.8 MB

  hipMemsetAsync(deg, 0, 800000, stream);    // deg + cnt (contiguous)
  hipMemsetAsync(flag, 0, 4, stream);

  k_detect   <<<16, 256, 0, stream>>>(ei, flag);
  k_wconv    <<<256, 256, 0, stream>>>(W1l, W1r, WtHi, WtLo);
  k_hist     <<<(E_TOT + 255) / 256, 256, 0, stream>>>(ei, flag, deg);
  k_seg_sum  <<<NSEG, 256, 0, stream>>>(deg, segsum);
  k_scan_small<<<1, 64, 0, stream>>>(segsum, segoff, rowptr);
  k_seg_scan <<<NSEG, 256, 0, stream>>>(deg, segoff, rowptr);
  k_scatter  <<<(E_TOT + 255) / 256, 256, 0, stream>>>(ei, flag, rowptr, cnt, esrc);
  k_gemm1    <<<(N_NODES + 127) / 128, 256, 0, stream>>>(x, WtHi, WtLo, xl1, xr1);
  k_edge1    <<<(N_NODES * HEADS) / 256, 256, 0, stream>>>(xl1, xr1, att1, b1, rowptr, esrc, hbuf);
  k_gemm2    <<<(N_NODES + 255) / 256, 256, 0, stream>>>(hbuf, W2l, W2r, xl2, xr2);
  k_edge2    <<<(N_NODES * HEADS) / 256, 256, 0, stream>>>(xl2, xr2, att2, b2, rowptr, esrc, out);
}